// Round 11
// baseline (37.104 us; speedup 1.0000x reference)
//
#include <hip/hip_runtime.h>

#define NSEG 16
#define BTHR 128

// ONE kernel, no workspace, no partials, no second launch.
// Grid = B*NSEG*2 = 256 blocks (1 per CU), 128 threads (2 waves).
// Block (bs, hh) computes the mean of its segment's rows over H-half hh:
// thread t owns float4 column hh*512 + t*4. Work-conserving tail: 16-row
// deep ILP gives each block ~256 B/thread in flight (~85 GB/s solo), so
// the heaviest block is never BW-starved once light blocks retire.
// vlen via 2-round ballot search: attention_mask is a prefix of ones
// (arange < lengths by construction), so valid_len = first-zero index.
__global__ void __launch_bounds__(BTHR) k_pool(
        const float* __restrict__ x, const int* __restrict__ mask,
        float* __restrict__ out, float* __restrict__ mout,
        int L, int H) {
    int bid = blockIdx.x;              // bs*2 + hh
    int hh = bid & 1;
    int bs = bid >> 1;
    int b = bs >> 4, s = bs & 15;
    int t = threadIdx.x;               // 0..127
    int lane = t & 63, wid = t >> 6;

    // ---- round 1: 128 probes at stride L/128 -> 32-wide window ----
    const int* m = mask + (size_t)b * L;
    __shared__ int sh[2];
    int stride = L >> 7;               // 32 for L=4096
    bool one1 = (m[t * stride] != 0);
    unsigned long long bal1 = __ballot(one1);
    if (lane == 0) sh[wid] = __popcll(bal1);
    __syncthreads();
    int m1 = sh[0] + sh[1];            // = ceil(vl/stride) >= 1 (vl >= 1)
    int a = (m1 - 1) * stride;         // vl in [a+1, a+stride]
    __syncthreads();
    // ---- round 2: wave 0 probes a+1 .. a+stride ----
    bool one2 = false;
    if (t < stride) {
        int p = a + 1 + t;
        one2 = (p < L) ? (m[p] != 0) : false;   // p==L can't be < vl
    }
    unsigned long long bal2 = __ballot(one2);
    if (t == 0) sh[0] = __popcll(bal2);
    __syncthreads();
    int vl = a + sh[0] + 1;

    // ---- segment geometry (exact integer boundaries) ----
    int start = (s * vl) >> 4;                       // s*vl < 2^24 -> exact
    int end   = ((s + 1) * vl) >> 4;                 // s==15 -> exactly vl
    int n = (start < vl) ? max(end - start, 1) : 0;  // rows to pool
    int cnt = max(end - start, 1);

    if (t == 0 && hh == 0) mout[bs] = (start < vl) ? 1.0f : 0.0f;

    // ---- stream n rows of this H-half, 16-row deep ILP ----
    const float* base = x + ((size_t)b * L + start) * H + hh * (H >> 1) + t * 4;
    float4 A[16];
    #pragma unroll
    for (int k = 0; k < 16; ++k) A[k] = make_float4(0.f, 0.f, 0.f, 0.f);

    int r = 0;
    for (; r + 16 <= n; r += 16) {
        #pragma unroll
        for (int k = 0; k < 16; ++k) {
            float4 v = *(const float4*)(base + (size_t)(r + k) * H);
            A[k].x += v.x; A[k].y += v.y; A[k].z += v.z; A[k].w += v.w;
        }
    }
    #pragma unroll 1
    for (; r < n; ++r) {
        float4 v = *(const float4*)(base + (size_t)r * H);
        A[0].x += v.x; A[0].y += v.y; A[0].z += v.z; A[0].w += v.w;
    }

    // ---- fixed-order pairwise tree (deterministic) ----
    #pragma unroll
    for (int st = 8; st > 0; st >>= 1) {
        #pragma unroll
        for (int k = 0; k < 8; ++k) {
            if (k < st) {
                A[k].x += A[k + st].x; A[k].y += A[k + st].y;
                A[k].z += A[k + st].z; A[k].w += A[k + st].w;
            }
        }
    }
    float scl = 1.0f / (float)cnt;     // n==0 -> A[0]==0 -> writes 0
    float4 o;
    o.x = A[0].x * scl; o.y = A[0].y * scl;
    o.z = A[0].z * scl; o.w = A[0].w * scl;
    *(float4*)(out + (size_t)bs * H + hh * (H >> 1) + t * 4) = o;
}

extern "C" void kernel_launch(void* const* d_in, const int* in_sizes, int n_in,
                              void* d_out, int out_size, void* d_ws, size_t ws_size,
                              hipStream_t stream) {
    const float* hs  = (const float*)d_in[0];
    const int* mask  = (const int*)d_in[1];
    int H = in_sizes[0] / in_sizes[1];          // 1024
    int B = out_size / (NSEG * (H + 1));        // 8
    int L = in_sizes[1] / B;                    // 4096

    float* seg_out  = (float*)d_out;
    float* mask_out = seg_out + (size_t)B * NSEG * H;

    k_pool<<<B * NSEG * 2, BTHR, 0, stream>>>(hs, mask, seg_out, mask_out, L, H);
}

// Round 12
// 18.965 us; speedup vs baseline: 1.9564x; 1.9564x over previous
//
#include <hip/hip_runtime.h>

#define NSEG 16
#define BTHR 1024

// ONE kernel, no workspace, no partials. Grid = B*NSEG*2 = 256 blocks
// (1 per CU), 1024 threads (16 waves). Block (bs, hh) computes the mean of
// its segment's rows over H-half hh. 8 row-groups x 128 threads; group g
// takes rows g, g+8, g+16, ... with 8-deep ILP (rows r0+{0,8,..,56}),
// so every group keeps 8 independent 16B loads in flight (per-CU in-flight
// ~128 KB -> ~110 GB/s solo, vs R10's 2-wave 14 GB/s). Remainder rows are
// handled inside the same predicated 8-deep unroll (conditions uniform per
// group -> cheap s_cbranch, no 1-deep latency tail). Deterministic: fixed
// row->group assignment + fixed pairwise reduction trees.
__global__ void __launch_bounds__(BTHR, 4) k_pool(
        const float* __restrict__ x, const int* __restrict__ mask,
        float* __restrict__ out, float* __restrict__ mout,
        int L, int H) {
    int bid = blockIdx.x;              // bs*2 + hh
    int hh = bid & 1;
    int bs = bid >> 1;
    int b = bs >> 4, s = bs & 15;
    int t = threadIdx.x;               // 0..1023
    int lane = t & 63, wid = t >> 6;   // 16 waves

    __shared__ int ish[16];
    __shared__ int vsh;
    __shared__ float4 red[8][128];     // 16 KB

    // ---- vl: block-reduce the 16 KB mask row (one int4 per thread) ----
    const int4* m4 = (const int4*)(mask + (size_t)b * L);
    int n4 = L >> 2;
    int acc = 0;
    for (int i = t; i < n4; i += BTHR) { int4 v = m4[i]; acc += v.x + v.y + v.z + v.w; }
    #pragma unroll
    for (int off = 32; off > 0; off >>= 1) acc += __shfl_down(acc, off, 64);
    if (lane == 0) ish[wid] = acc;
    __syncthreads();
    if (t == 0) {
        int v = 0;
        #pragma unroll
        for (int w = 0; w < 16; ++w) v += ish[w];
        vsh = v;
    }
    __syncthreads();
    int vl = vsh;

    // ---- segment geometry (exact integer boundaries) ----
    int start = (s * vl) >> 4;                       // s*vl < 2^24 -> exact
    int end   = ((s + 1) * vl) >> 4;                 // s==15 -> exactly vl
    int n = (start < vl) ? max(end - start, 1) : 0;  // rows to pool (<= 256)
    int cnt = max(end - start, 1);

    if (hh == 0 && t == 0) mout[bs] = (start < vl) ? 1.0f : 0.0f;

    // ---- stream: group g, rows g+8k, 8-deep ILP ----
    int g = t >> 7;                    // row-group 0..7
    int c4 = t & 127;                  // float4 column within half-row
    const float* base = x + ((size_t)b * L + start) * H + hh * (H >> 1) + c4 * 4;

    float4 A[8];
    #pragma unroll
    for (int k = 0; k < 8; ++k) A[k] = make_float4(0.f, 0.f, 0.f, 0.f);

    for (int r0 = g; r0 < n; r0 += 64) {
        #pragma unroll
        for (int k = 0; k < 8; ++k) {
            int r = r0 + k * 8;
            if (r < n) {               // uniform within the group's waves
                float4 v = *(const float4*)(base + (size_t)r * H);
                A[k].x += v.x; A[k].y += v.y; A[k].z += v.z; A[k].w += v.w;
            }
        }
    }

    // ---- fixed-order pairwise tree over the 8 ILP accumulators ----
    float4 o;
    o.x = ((A[0].x + A[1].x) + (A[2].x + A[3].x)) + ((A[4].x + A[5].x) + (A[6].x + A[7].x));
    o.y = ((A[0].y + A[1].y) + (A[2].y + A[3].y)) + ((A[4].y + A[5].y) + (A[6].y + A[7].y));
    o.z = ((A[0].z + A[1].z) + (A[2].z + A[3].z)) + ((A[4].z + A[5].z) + (A[6].z + A[7].z));
    o.w = ((A[0].w + A[1].w) + (A[2].w + A[3].w)) + ((A[4].w + A[5].w) + (A[6].w + A[7].w));
    red[g][c4] = o;
    __syncthreads();

    // ---- fixed-order tree over the 8 row-groups, scale, write ----
    if (t < 128) {
        float4 r0 = red[0][t], r1 = red[1][t], r2 = red[2][t], r3 = red[3][t];
        float4 r4 = red[4][t], r5 = red[5][t], r6 = red[6][t], r7 = red[7][t];
        float4 q;
        q.x = ((r0.x + r1.x) + (r2.x + r3.x)) + ((r4.x + r5.x) + (r6.x + r7.x));
        q.y = ((r0.y + r1.y) + (r2.y + r3.y)) + ((r4.y + r5.y) + (r6.y + r7.y));
        q.z = ((r0.z + r1.z) + (r2.z + r3.z)) + ((r4.z + r5.z) + (r6.z + r7.z));
        q.w = ((r0.w + r1.w) + (r2.w + r3.w)) + ((r4.w + r5.w) + (r6.w + r7.w));
        float scl = 1.0f / (float)cnt;   // n==0 -> all zeros -> writes 0
        q.x *= scl; q.y *= scl; q.z *= scl; q.w *= scl;
        *(float4*)(out + (size_t)bs * H + hh * (H >> 1) + t * 4) = q;
    }
}

extern "C" void kernel_launch(void* const* d_in, const int* in_sizes, int n_in,
                              void* d_out, int out_size, void* d_ws, size_t ws_size,
                              hipStream_t stream) {
    const float* hs  = (const float*)d_in[0];
    const int* mask  = (const int*)d_in[1];
    int H = in_sizes[0] / in_sizes[1];          // 1024
    int B = out_size / (NSEG * (H + 1));        // 8
    int L = in_sizes[1] / B;                    // 4096

    float* seg_out  = (float*)d_out;
    float* mask_out = seg_out + (size_t)B * NSEG * H;

    k_pool<<<B * NSEG * 2, BTHR, 0, stream>>>(hs, mask, seg_out, mask_out, L, H);
}